// Round 14
// baseline (209.587 us; speedup 1.0000x reference)
//
#include <hip/hip_runtime.h>

#define K_ITERS 20
#define MU_CONST 0.05f
#define BN 128
#define YSTRIDE 24      // float stride between 16-float y slices (bank spread)

typedef float v4f __attribute__((ext_vector_type(4)));
typedef __attribute__((address_space(1))) const v4f gc4;   // global const float4
typedef __attribute__((address_space(1))) v4f g4;          // global float4
typedef const __attribute__((address_space(1))) void* gas_ptr;
typedef __attribute__((address_space(3))) void* las_ptr;

// DPP butterfly add step (pure VALU cross-lane; ctrl must be immediate).
template <int CTRL>
__device__ __forceinline__ float dpp_add(float v) {
    int x = __builtin_amdgcn_update_dpp(0, __float_as_int(v), CTRL, 0xF, 0xF, true);
    return v + __int_as_float(x);
}
// sum over the 8 lanes sharing a row-quad (lane bits [2:0] = col-group g)
__device__ __forceinline__ float reduce8(float v) {
    v = dpp_add<0xB1>(v);   // quad_perm xor1
    v = dpp_add<0x4E>(v);   // quad_perm xor2
    v = dpp_add<0x141>(v);  // row_half_mirror
    return v;
}

// 2048 blocks x 256 threads, 2 batches per block, 4 blocks/CU.
// R13's probe made real: during batch0's compute, rows 0..63 of batch1's w
// stream into a 32 KiB LDS stage via un-waited global_load_lds (proven to
// ride through the raw lgkm-only barriers and absorb into HBM port slack).
// At the switch: one vmcnt(0), copy staged half to regs (waves 0,1), direct
// global loads for rows 64..127 (waves 2,3 - wave-uniform split).
__global__ __launch_bounds__(256, 4) void nag_kernel(
    const float* __restrict__ w,
    const float* __restrict__ bvec,
    const float* __restrict__ s_ptr,
    float* __restrict__ out,
    int B)
{
    __shared__ __align__(16) float stage[64 * BN];          // 32 KiB: b1 rows 0..63
    __shared__ __align__(16) float y_lds[2][8 * YSTRIDE];   // ping-pong y

    const int t    = threadIdx.x;     // 0..255
    const int lane = t & 63;
    const int wv   = t >> 6;          // wave 0..3
    const int q    = (t >> 3) & 7;    // row-quad within wave
    const int g    = t & 7;           // col-group (16 cols)
    const int row0   = wv * 32 + q * 4;
    const int wslice = (row0 >> 4) * YSTRIDE + (q & 3) * 4;  // y write offset
    const int rbase  = g * YSTRIDE;                          // y read offset

    const int b0 = blockIdx.x * 2;
    const int b1 = b0 + 1;

    // prologue: batch0 w -> regs (R7 pattern), both b vectors, s
    v4f w4[4][4];
    const gc4* wp = (const gc4*)(w + (size_t)b0 * (BN * BN)
                                   + (size_t)row0 * BN + g * 16);
#pragma unroll
    for (int rho = 0; rho < 4; ++rho)
#pragma unroll
        for (int k = 0; k < 4; ++k)
            w4[rho][k] = wp[rho * 32 + k];

    const v4f brA = *(const gc4*)(bvec + (size_t)b0 * BN + row0);
    const v4f brB = *(const gc4*)(bvec + (size_t)b1 * BN + row0);

    const float s     = *s_ptr;
    const float sqms  = sqrtf(MU_CONST * s);
    const float alpha = (1.0f - sqms) / (1.0f + sqms);
    const float ap1   = 1.0f + alpha;

    // next-batch stage source (rows 0..63); swizzled global source so the
    // strided read-back un-swizzles (both-sides rule, R6-proven pair)
    const float* wn = w + (size_t)b1 * (BN * BN);

    auto body = [&](int batch, const v4f br4, bool pf) {
        const float br_[4] = {br4.x, br4.y, br4.z, br4.w};

        // closed-form step 1 (y0 = 0): x1 = s*b, y1 = (1+alpha)*x1
        float xs[4], ys[4];
#pragma unroll
        for (int rho = 0; rho < 4; ++rho) {
            xs[rho] = s * br_[rho];
            ys[rho] = ap1 * xs[rho];
        }
        if (g == 0)
            *reinterpret_cast<v4f*>(&y_lds[0][wslice]) =
                (v4f){ys[0], ys[1], ys[2], ys[3]};
        __builtin_amdgcn_sched_barrier(0);
        asm volatile("s_waitcnt lgkmcnt(0)");
        __builtin_amdgcn_s_barrier();
        __builtin_amdgcn_sched_barrier(0);

#pragma unroll 2
        for (int it = 1; it < K_ITERS; ++it) {
            const float* yb = &y_lds[(it + 1) & 1][rbase];
            v4f yv[4];
#pragma unroll
            for (int k = 0; k < 4; ++k)
                yv[k] = *reinterpret_cast<const v4f*>(yb + k * 4);

            // prefetch: 8 x 1 KiB DMA per wave (rows 0..63 of b1), un-waited
            if (pf && it == 2) {
#pragma unroll
                for (int cc = 0; cc < 8; ++cc) {
                    const int inst = wv * 8 + cc;            // 0..31
                    const int rho  = inst * 2 + (lane >> 5); // row 0..63
                    const int c4   = lane & 31;
                    const int G    = rho * 32 + (c4 ^ (rho & 7));
                    __builtin_amdgcn_global_load_lds(
                        (gas_ptr)(wn + (size_t)G * 4),
                        (las_ptr)(stage + inst * 256), 16, 0, 0);
                }
            }

#pragma unroll
            for (int rho = 0; rho < 4; ++rho) {
                float p = w4[rho][0].x * yv[0].x;
                p = fmaf(w4[rho][0].y, yv[0].y, p);
                p = fmaf(w4[rho][0].z, yv[0].z, p);
                p = fmaf(w4[rho][0].w, yv[0].w, p);
                p = fmaf(w4[rho][1].x, yv[1].x, p);
                p = fmaf(w4[rho][1].y, yv[1].y, p);
                p = fmaf(w4[rho][1].z, yv[1].z, p);
                p = fmaf(w4[rho][1].w, yv[1].w, p);
                p = fmaf(w4[rho][2].x, yv[2].x, p);
                p = fmaf(w4[rho][2].y, yv[2].y, p);
                p = fmaf(w4[rho][2].z, yv[2].z, p);
                p = fmaf(w4[rho][2].w, yv[2].w, p);
                p = fmaf(w4[rho][3].x, yv[3].x, p);
                p = fmaf(w4[rho][3].y, yv[3].y, p);
                p = fmaf(w4[rho][3].z, yv[3].z, p);
                p = fmaf(w4[rho][3].w, yv[3].w, p);
                const float d  = reduce8(p);           // full 128-col dot
                const float xn = fmaf(-s, d - br_[rho], ys[rho]);
                ys[rho] = fmaf(ap1, xn, -(alpha * xs[rho]));
                xs[rho] = xn;
            }

            if (it != K_ITERS - 1 && g == 0)
                *reinterpret_cast<v4f*>(&y_lds[it & 1][wslice]) =
                    (v4f){ys[0], ys[1], ys[2], ys[3]};

            // raw barrier: drains LDS only; prefetch vmcnt stays in flight
            __builtin_amdgcn_sched_barrier(0);
            asm volatile("s_waitcnt lgkmcnt(0)");
            __builtin_amdgcn_s_barrier();
            __builtin_amdgcn_sched_barrier(0);
        }

        // outputs: x then y, each B*BN flat; rows row0..row0+3 contiguous
        const size_t ob = (size_t)batch * BN + row0;
        if (g == 0)
            *(g4*)(out + ob) = (v4f){xs[0], xs[1], xs[2], xs[3]};
        else if (g == 1)
            *(g4*)(out + (size_t)B * BN + ob) = (v4f){ys[0], ys[1], ys[2], ys[3]};
    };

    // ---- batch 0 (prefetches b1 rows 0..63 into stage) ----
    body(b0, brA, true);

    // ---- switch to batch 1 ----
    if (row0 >= 64) {                 // waves 2,3: direct loads rows 64..127
        const gc4* wp1 = (const gc4*)(w + (size_t)b1 * (BN * BN)
                                        + (size_t)row0 * BN + g * 16);
#pragma unroll
        for (int rho = 0; rho < 4; ++rho)
#pragma unroll
            for (int k = 0; k < 4; ++k)
                w4[rho][k] = wp1[rho * 32 + k];
    }
    __builtin_amdgcn_sched_barrier(0);
    asm volatile("s_waitcnt vmcnt(0)");      // stage DMAs (and direct) landed
    __builtin_amdgcn_s_barrier();
    __builtin_amdgcn_sched_barrier(0);
    if (row0 < 64) {                  // waves 0,1: copy staged half to regs
        const v4f* st4 = (const v4f*)stage;
#pragma unroll
        for (int rr = 0; rr < 4; ++rr) {
            const int rho = row0 + rr;
            const int sw  = rho & 7;
#pragma unroll
            for (int k = 0; k < 4; ++k)
                w4[rr][k] = st4[rho * 32 + ((g * 4 + k) ^ sw)];
        }
    }
    __builtin_amdgcn_sched_barrier(0);
    asm volatile("s_waitcnt lgkmcnt(0)");
    __builtin_amdgcn_s_barrier();
    __builtin_amdgcn_sched_barrier(0);

    // ---- batch 1 (no prefetch) ----
    body(b1, brB, false);
}

extern "C" void kernel_launch(void* const* d_in, const int* in_sizes, int n_in,
                              void* d_out, int out_size, void* d_ws, size_t ws_size,
                              hipStream_t stream) {
    const float* w = (const float*)d_in[0];
    const float* b = (const float*)d_in[1];
    const float* s = (const float*)d_in[2];
    float* out = (float*)d_out;
    const int B = in_sizes[1] / BN;    // 4096
    nag_kernel<<<dim3(B / 2), dim3(256), 0, stream>>>(w, b, s, out, B);
}

// Round 15
// 84.383 us; speedup vs baseline: 2.4838x; 2.4838x over previous
//
#include <hip/hip_runtime.h>

#define K_ITERS 20
#define MU_CONST 0.05f
#define BN 128
#define YSTRIDE 24      // float stride between 16-float y slices (bank spread)
#define PF_DIST 1024    // one residency generation (4 blk/CU x 256 CU)

typedef float v4f __attribute__((ext_vector_type(4)));
typedef __attribute__((address_space(1))) const v4f gc4;   // global const float4
typedef __attribute__((address_space(1))) v4f g4;          // global float4
typedef const __attribute__((address_space(1))) void* gas_ptr;
typedef __attribute__((address_space(3))) void* las_ptr;

// DPP butterfly add step (pure VALU cross-lane; ctrl must be immediate).
template <int CTRL>
__device__ __forceinline__ float dpp_add(float v) {
    int x = __builtin_amdgcn_update_dpp(0, __float_as_int(v), CTRL, 0xF, 0xF, true);
    return v + __int_as_float(x);
}
// sum over the 8 lanes sharing a row-quad (lane bits [2:0] = col-group g)
__device__ __forceinline__ float reduce8(float v) {
    v = dpp_add<0xB1>(v);   // quad_perm xor1
    v = dpp_add<0x4E>(v);   // quad_perm xor2
    v = dpp_add<0x141>(v);  // row_half_mirror
    return v;
}

// R13 structure (proven: un-waited DMAs absorb into HBM port slack under the
// raw lgkm-only barriers), with the probe RETARGETED to batch+1024:
// each block streams the w of the block one residency-generation ahead into
// a write-only LDS sink -> lines land in L3 (and same-XCD L2, %8 dispatch).
// Generation g+1's blocking register loads then hit cache instead of HBM;
// HBM streaming rides under compute. Gen 1 cold (ramp); last gen: no probe.
__global__ __launch_bounds__(256, 4) void nag_kernel(
    const float* __restrict__ w,
    const float* __restrict__ bvec,
    const float* __restrict__ s_ptr,
    float* __restrict__ out,
    int B)
{
    __shared__ __align__(16) float y_lds[2][8 * YSTRIDE];   // ping-pong y
    __shared__ __align__(16) float probe_sink[4][256];      // 4 KiB write-only

    const int t    = threadIdx.x;     // 0..255
    const int lane = t & 63;
    const int wv   = t >> 6;          // wave 0..3
    const int q    = (t >> 3) & 7;    // row-quad within wave
    const int g    = t & 7;           // col-group (16 cols)
    const int row0   = wv * 32 + q * 4;
    const int wslice = (row0 >> 4) * YSTRIDE + (q & 3) * 4;  // y write offset
    const int rbase  = g * YSTRIDE;                          // y read offset

    const int batch = blockIdx.x;

    // issue all global loads: 16x dwordx4 (w) + 1x dwordx4 (b) + s
    v4f w4[4][4];
    const gc4* wp = (const gc4*)(w + (size_t)batch * (BN * BN)
                                   + (size_t)row0 * BN + g * 16);
#pragma unroll
    for (int rho = 0; rho < 4; ++rho)
#pragma unroll
        for (int k = 0; k < 4; ++k)
            w4[rho][k] = wp[rho * 32 + k];

    const v4f br4 = *(const gc4*)(bvec + (size_t)batch * BN + row0);
    const float br_[4] = {br4.x, br4.y, br4.z, br4.w};

    const float s     = *s_ptr;
    const float sqms  = sqrtf(MU_CONST * s);
    const float alpha = (1.0f - sqms) / (1.0f + sqms);
    const float ap1   = 1.0f + alpha;

    // prefetch target: one generation ahead (same XCD); none for last gen
    const int  pb   = batch + PF_DIST;
    const bool dopf = pb < B;
    const float* wn = w + (size_t)(dopf ? pb : 0) * (BN * BN)
                        + (size_t)wv * 4096;

    // closed-form step 1 (y0 = 0): x1 = s*b, y1 = (1+alpha)*x1
    float xs[4], ys[4];
#pragma unroll
    for (int rho = 0; rho < 4; ++rho) {
        xs[rho] = s * br_[rho];
        ys[rho] = ap1 * xs[rho];
    }
    if (g == 0)
        *reinterpret_cast<v4f*>(&y_lds[0][wslice]) =
            (v4f){ys[0], ys[1], ys[2], ys[3]};
    __syncthreads();   // prologue: also drains w4/b loads (needed anyway)

#pragma unroll 2
    for (int it = 1; it < K_ITERS; ++it) {
        const float* yb = &y_lds[(it + 1) & 1][rbase];
        v4f yv[4];
#pragma unroll
        for (int k = 0; k < 4; ++k)
            yv[k] = *reinterpret_cast<const v4f*>(yb + k * 4);

        // ---- L3-warming prefetch: 64 KiB of batch+1024, never waited ----
        if (dopf && it == 2) {
#pragma unroll
            for (int j = 0; j < 16; ++j)
                __builtin_amdgcn_global_load_lds(
                    (gas_ptr)(wn + j * 256 + lane * 4),
                    (las_ptr)(&probe_sink[wv][0]), 16, 0, 0);
        }

#pragma unroll
        for (int rho = 0; rho < 4; ++rho) {
            float p = w4[rho][0].x * yv[0].x;
            p = fmaf(w4[rho][0].y, yv[0].y, p);
            p = fmaf(w4[rho][0].z, yv[0].z, p);
            p = fmaf(w4[rho][0].w, yv[0].w, p);
            p = fmaf(w4[rho][1].x, yv[1].x, p);
            p = fmaf(w4[rho][1].y, yv[1].y, p);
            p = fmaf(w4[rho][1].z, yv[1].z, p);
            p = fmaf(w4[rho][1].w, yv[1].w, p);
            p = fmaf(w4[rho][2].x, yv[2].x, p);
            p = fmaf(w4[rho][2].y, yv[2].y, p);
            p = fmaf(w4[rho][2].z, yv[2].z, p);
            p = fmaf(w4[rho][2].w, yv[2].w, p);
            p = fmaf(w4[rho][3].x, yv[3].x, p);
            p = fmaf(w4[rho][3].y, yv[3].y, p);
            p = fmaf(w4[rho][3].z, yv[3].z, p);
            p = fmaf(w4[rho][3].w, yv[3].w, p);
            const float d  = reduce8(p);           // full 128-col dot
            const float xn = fmaf(-s, d - br_[rho], ys[rho]);
            ys[rho] = fmaf(ap1, xn, -(alpha * xs[rho]));
            xs[rho] = xn;
        }

        if (it != K_ITERS - 1 && g == 0)
            *reinterpret_cast<v4f*>(&y_lds[it & 1][wslice]) =
                (v4f){ys[0], ys[1], ys[2], ys[3]};

        // raw barrier: drains LDS only; probe vmcnt stays in flight
        __builtin_amdgcn_sched_barrier(0);
        asm volatile("s_waitcnt lgkmcnt(0)");
        __builtin_amdgcn_s_barrier();
        __builtin_amdgcn_sched_barrier(0);
    }

    // outputs: x then y, each B*BN flat; rows row0..row0+3 contiguous
    const size_t ob = (size_t)batch * BN + row0;
    if (g == 0)
        *(g4*)(out + ob) = (v4f){xs[0], xs[1], xs[2], xs[3]};
    else if (g == 1)
        *(g4*)(out + (size_t)B * BN + ob) = (v4f){ys[0], ys[1], ys[2], ys[3]};
}

extern "C" void kernel_launch(void* const* d_in, const int* in_sizes, int n_in,
                              void* d_out, int out_size, void* d_ws, size_t ws_size,
                              hipStream_t stream) {
    const float* w = (const float*)d_in[0];
    const float* b = (const float*)d_in[1];
    const float* s = (const float*)d_in[2];
    float* out = (float*)d_out;
    const int B = in_sizes[1] / BN;    // 4096
    nag_kernel<<<dim3(B), dim3(256), 0, stream>>>(w, b, s, out, B);
}